// Round 16
// baseline (131.825 us; speedup 1.0000x reference)
//
#include <hip/hip_runtime.h>
#include <hip/hip_bf16.h>
#include <math.h>

#define NROWS 32768
#define DD    1024
#define EE    640
#define VV    320
#define BMR   128     // rows per block
#define KT2   16      // DD/64
#define CTN   40      // EE/16

typedef __attribute__((ext_vector_type(4))) float float4v;
typedef long long i64t;

static __device__ __forceinline__ void gload_lds16(const void* g, void* l) {
    __builtin_amdgcn_global_load_lds(
        (const __attribute__((address_space(1))) unsigned int*)g,
        (__attribute__((address_space(3))) unsigned int*)l, 16, 0, 0);
}

// Pack W [K=1024][N=640] fp32 -> fp8 e4m3 (scaled x16), MFMA fragment layout:
// frag(kt32, ct): lane l, elem e <= 16*W[kt32*32 + (l>>4)*8 + e][ct*16 + (l&15)]
__global__ void pack_w8(const float* __restrict__ W, unsigned char* __restrict__ bp)
{
    const int t = threadIdx.x;
    const int tile = blockIdx.x * 4 + (t >> 6);   // 0..1279 = kt32*40+ct
    const int lane = t & 63;
    const int kt = tile / CTN, ct = tile % CTN;
    const int k0 = kt * 32 + (lane >> 4) * 8;
    const int col = ct * 16 + (lane & 15);
    float v[8];
    #pragma unroll
    for (int e = 0; e < 8; ++e)
        v[e] = 16.0f * W[(size_t)(k0 + e) * EE + col];
    int lo = 0, hi = 0;
    lo = __builtin_amdgcn_cvt_pk_fp8_f32(v[0], v[1], lo, false);
    lo = __builtin_amdgcn_cvt_pk_fp8_f32(v[2], v[3], lo, true);
    hi = __builtin_amdgcn_cvt_pk_fp8_f32(v[4], v[5], hi, false);
    hi = __builtin_amdgcn_cvt_pk_fp8_f32(v[6], v[7], hi, true);
    int2 pk; pk.x = lo; pk.y = hi;
    *(int2*)(bp + ((size_t)tile * 64 + lane) * 8) = pk;
}

// Fused, group-split: 512 blocks x 512 threads = 2 blocks/CU (LDS ~65KB).
// Block = (row-tile rt, group g): 128 rows x this group's 320 cols. XCD
// swizzle co-locates both g-blocks of an rt on one XCD (x L2-dedup).
// 8 waves: rg=w>>2 (64-row half), cg=w&3 (80-col group). acc[4][5].
// BK=64 (KT2=16 barriers, half of R15). B: 2x20KB fp8 dbuf; A: 2x8KB fp8 dbuf.
__global__ __launch_bounds__(512, 4) void fused_vq(
    const float* __restrict__ x, const unsigned char* __restrict__ bp,
    const float* __restrict__ bias, const float* __restrict__ cb,
    const float* __restrict__ gum, float* __restrict__ out,
    float* __restrict__ probs_rep)
{
    __shared__ unsigned char Bs[2][20480];        // 2 x 20 KB (2 ksub x 20 frags)
    __shared__ unsigned char As[2][8192];         // 2 x 8 KB (8 rowfrag x 2 ksub)
    __shared__ float probs_blk[VV];
    __shared__ float pmax[4][BMR];
    __shared__ float psum[4][BMR];
    __shared__ int   pidx[4][BMR];
    __shared__ int   fidx[BMR];
    __shared__ float finv[BMR];

    const int t    = threadIdx.x;
    const int lane = t & 63;
    const int w    = t >> 6;
    const int rg   = w >> 2;            // 64-row half
    const int cg   = w & 3;             // 80-col group within the 320-col group

    const int p  = blockIdx.x;          // XCD-pairing swizzle (8 XCDs)
    const int g  = (p >> 3) & 1;
    const int rt = (p & 7) * 32 + (p >> 4);
    const int n0 = rt * BMR;

    float4v acc[4][5];
    #pragma unroll
    for (int rf = 0; rf < 4; ++rf)
        #pragma unroll
        for (int ct = 0; ct < 5; ++ct)
            acc[rf][ct] = (float4v)0.f;

    // ---- A staging map: thread t stages quads Q = t + s*512 (s=0..3) ----
    int aoff[4]; const float* xq[4];
    #pragma unroll
    for (int s = 0; s < 4; ++s) {
        const int Q = t + s * 512;
        const int row = Q >> 4, kq = Q & 15;
        aoff[s] = ((row >> 4)*2 + (kq >> 3))*512
                + ((((kq & 7) >> 1) << 4) + (row & 15))*8 + ((kq & 1) << 2);
        xq[s] = x + (size_t)(n0 + row) * DD + kq * 4;
    }
    auto writeA = [&](int bb, const float4* v) {
        #pragma unroll
        for (int s = 0; s < 4; ++s) {
            int pk = 0;
            pk = __builtin_amdgcn_cvt_pk_fp8_f32(v[s].x, v[s].y, pk, false);
            pk = __builtin_amdgcn_cvt_pk_fp8_f32(v[s].z, v[s].w, pk, true);
            *(int*)&As[bb][aoff[s]] = pk;
        }
    };
    // ---- B staging: 20KB/kt = frags [2kt][g*20..+19] ++ [2kt+1][g*20..+19] ----
    auto stageB = [&](int bb, int kt) {
        const unsigned char* s0 = bp + (((size_t)(2*kt)   * CTN) + g*20) * 512;
        const unsigned char* s1 = bp + (((size_t)(2*kt+1) * CTN) + g*20) * 512;
        unsigned char* d = &Bs[bb][0];
        gload_lds16(s0 + (size_t)t*16, d + t*16);                       // 0..8191
        if (t < 128) gload_lds16(s0 + 8192 + (size_t)t*16, d + 8192 + t*16);   // 8192..10239
        else         gload_lds16(s1 + (size_t)(t-128)*16,  d + 10240 + (t-128)*16); // ksub1 0..6143
        if (t < 256) gload_lds16(s1 + (size_t)(t+384)*16,  d + 10240 + (t+384)*16); // ksub1 6144..10239
    };

    // prologue: stage kt=0
    float4 pA[4];
    #pragma unroll
    for (int s = 0; s < 4; ++s) pA[s] = *(const float4*)(xq[s]);
    stageB(0, 0);
    __syncthreads();              // all loads drained
    writeA(0, pA);
    __syncthreads();

    for (int kt = 0; kt < KT2; ++kt) {
        const int bb = kt & 1;
        const bool more = (kt + 1 < KT2);
        float4 pN[4];
        if (more) {
            stageB(bb ^ 1, kt + 1);                       // async, overlaps compute
            #pragma unroll
            for (int s = 0; s < 4; ++s)
                pN[s] = *(const float4*)(xq[s] + (kt + 1) * 64);
        }
        i64t af[4][2];
        #pragma unroll
        for (int rf = 0; rf < 4; ++rf)
            #pragma unroll
            for (int ks = 0; ks < 2; ++ks)
                af[rf][ks] = *(const i64t*)&As[bb][((rg*4 + rf)*2 + ks)*512 + lane*8];
        #pragma unroll
        for (int ks = 0; ks < 2; ++ks) {
            #pragma unroll
            for (int ct = 0; ct < 5; ++ct) {
                i64t bf = *(const i64t*)&Bs[bb][(ks*20 + cg*5 + ct)*512 + lane*8];
                #pragma unroll
                for (int rf = 0; rf < 4; ++rf)
                    acc[rf][ct] = __builtin_amdgcn_mfma_f32_16x16x32_fp8_fp8(af[rf][ks], bf, acc[rf][ct], 0, 0, 0);
            }
        }
        if (more) writeA(bb ^ 1, pN);                     // write-late
        __syncthreads();          // one barrier per kt (16 total)
    }

    // un-scale (W was x16) + bias (zeros here; kept faithful)
    const int col0 = cg*80 + (lane & 15);                 // col within group
    {
        float bv[5];
        #pragma unroll
        for (int ct = 0; ct < 5; ++ct) bv[ct] = bias[g*VV + col0 + ct*16];
        #pragma unroll
        for (int rf = 0; rf < 4; ++rf)
            #pragma unroll
            for (int ct = 0; ct < 5; ++ct)
                #pragma unroll
                for (int r = 0; r < 4; ++r)
                    acc[rf][ct][r] = acc[rf][ct][r] * 0.0625f + bv[ct];
    }

    // ---- Phase A: gumbel-argmax partial + clean exp-sum partial ----
    #pragma unroll
    for (int rf = 0; rf < 4; ++rf) {
        #pragma unroll
        for (int r = 0; r < 4; ++r) {
            const int rowA = rg*64 + rf*16 + ((lane >> 4) << 2) + r;
            const float* grow = gum + ((size_t)(n0 + rowA)*2 + g)*VV + col0;
            float m1 = -1e30f; int bi = 0; float es = 0.f;
            #pragma unroll
            for (int ct = 0; ct < 5; ++ct) {
                float zv = acc[rf][ct][r];
                float zg = zv + grow[ct*16];
                if (zg > m1) { m1 = zg; bi = col0 + ct*16; }
                es += __expf(zv);
            }
            #pragma unroll
            for (int off = 1; off < 16; off <<= 1) {
                float om = __shfl_xor(m1, off);
                int   ob = __shfl_xor(bi, off);
                if (om > m1 || (om == m1 && ob < bi)) { m1 = om; bi = ob; }
                es += __shfl_xor(es, off);
            }
            if ((lane & 15) == 0) {
                pmax[cg][rowA] = m1; pidx[cg][rowA] = bi; psum[cg][rowA] = es;
            }
        }
    }
    if (t < VV) probs_blk[t] = 0.f;
    __syncthreads();

    // ---- Phase B: combine 4 col-wave partials per row ----
    if (t < BMR) {
        const int row = t;
        float m1 = -1e30f; int bi = 0x7fffffff; float s = 0.f;
        #pragma unroll
        for (int c = 0; c < 4; ++c) {
            const float om = pmax[c][row];
            const int   ob = pidx[c][row];
            if (om > m1 || (om == m1 && ob < bi)) { m1 = om; bi = ob; }
            s += psum[c][row];
        }
        fidx[row] = bi;
        finv[row] = 1.f / s;
    }
    __syncthreads();

    // ---- Phase C: probs accumulation (this group's 320 cols) ----
    float pacc[5];
    #pragma unroll
    for (int ct = 0; ct < 5; ++ct) pacc[ct] = 0.f;
    #pragma unroll
    for (int rf = 0; rf < 4; ++rf) {
        #pragma unroll
        for (int r = 0; r < 4; ++r) {
            const int rowA = rg*64 + rf*16 + ((lane >> 4) << 2) + r;
            const float inv = finv[rowA];
            #pragma unroll
            for (int ct = 0; ct < 5; ++ct)
                pacc[ct] += __expf(acc[rf][ct][r]) * inv;
        }
    }
    #pragma unroll
    for (int off = 16; off < 64; off <<= 1)
        #pragma unroll
        for (int ct = 0; ct < 5; ++ct)
            pacc[ct] += __shfl_xor(pacc[ct], off);
    if (lane < 16) {
        #pragma unroll
        for (int ct = 0; ct < 5; ++ct)
            atomicAdd(&probs_blk[cg*80 + ct*16 + lane], pacc[ct]);
    }
    __syncthreads();

    const int rep = p & 7;
    if (t < VV)
        atomicAdd(&probs_rep[rep*EE + g*VV + t], probs_blk[t]);

    // ---- output: this group's 512-wide half of each row (coalesced) ----
    for (int i = t; i < BMR * 128; i += 512) {
        const int row = i >> 7, f4 = i & 127;
        const int idx = fidx[row];
        const float4 v = *(const float4*)&cb[((size_t)g*VV + idx)*512 + (size_t)f4*4];
        *(float4*)&out[(size_t)(n0 + row)*DD + g*512 + (size_t)f4*4] = v;
    }
}

// perplexity from 8-replica probs accumulator
__global__ void perp8_kernel(const float* __restrict__ probs_rep,
                             float* __restrict__ outp)
{
    __shared__ float s0[4], s1[4];
    int t = threadIdx.x;   // 256
    float p0 = 0.f, p1 = 0.f;
    for (int c = t; c < EE; c += 256) {
        float a = 0.f;
        #pragma unroll
        for (int rp = 0; rp < 8; ++rp) a += probs_rep[rp*EE + c];
        a *= (1.0f / NROWS);
        float v = a * logf(a + 1e-7f);
        if (c < VV) p0 += v; else p1 += v;
    }
    #pragma unroll
    for (int off = 1; off < 64; off <<= 1) {
        p0 += __shfl_xor(p0, off);
        p1 += __shfl_xor(p1, off);
    }
    if ((t & 63) == 0) { s0[t >> 6] = p0; s1[t >> 6] = p1; }
    __syncthreads();
    if (t == 0) {
        float a0 = s0[0] + s0[1] + s0[2] + s0[3];
        float a1 = s1[0] + s1[1] + s1[2] + s1[3];
        outp[0] = 0.5f * (expf(-a0) + expf(-a1));
    }
}

extern "C" void kernel_launch(void* const* d_in, const int* in_sizes, int n_in,
                              void* d_out, int out_size, void* d_ws, size_t ws_size,
                              hipStream_t stream)
{
    const float* x   = (const float*)d_in[0];
    const float* W   = (const float*)d_in[1];
    const float* b   = (const float*)d_in[2];
    const float* cb  = (const float*)d_in[3];
    const float* gum = (const float*)d_in[4];
    float* out = (float*)d_out;

    // ws layout: [bp8 640KB][probs_rep 20KB]
    char* wsp = (char*)d_ws;
    unsigned char* bp = (unsigned char*)wsp;
    const size_t bp_b = (size_t)DD*EE;            // fp8: 1 byte/elem
    float* probs_rep = (float*)(wsp + bp_b);
    const size_t pr_b = 8*EE*sizeof(float);

    hipMemsetAsync(probs_rep, 0, pr_b, stream);
    pack_w8<<<320, 256, 0, stream>>>(W, bp);
    fused_vq<<<512, 512, 0, stream>>>(x, bp, b, cb, gum, out, probs_rep);
    perp8_kernel<<<1, 256, 0, stream>>>(probs_rep, out + (out_size - 1));
}